// Round 1
// baseline (5037.943 us; speedup 1.0000x reference)
//
#include <hip/hip_runtime.h>
#include <hip/hip_bf16.h>

#define B_ 4
#define N_ 2048
#define C_ 1024
#define H_ 16
#define D_ 64
#define SCALE_ 0.125f

// ---------------- tiled f32 GEMM: out[m][o] = sum_k A[m][k] * W[o][k] ----------------
#define GTM 64
#define GTN 64
#define GTK 16

__global__ __launch_bounds__(256) void qkv_gemm_kernel(
    const float* __restrict__ X,        // [8192, 1024]
    const float* __restrict__ W,        // [3072, 1024]
    const float* __restrict__ qkv_b,    // [3072]
    const float* __restrict__ bias_mask,// [3072]
    float* __restrict__ Qb, float* __restrict__ Kb, float* __restrict__ Vb) // each [B,H,N,D]
{
    __shared__ float As[GTK][GTM + 4];
    __shared__ float Bs[GTK][GTN + 4];
    const int bm = blockIdx.x * GTM;
    const int bo = blockIdx.y * GTN;
    const int tid = threadIdx.x;
    const int lm = tid >> 2;          // 0..63
    const int lk = (tid & 3) << 2;    // 0,4,8,12
    const int tm = (tid >> 4) << 2;   // 0..60
    const int tn = (tid & 15) << 2;   // 0..60
    float acc[4][4] = {};
    const float* xg = X + (size_t)(bm + lm) * C_ + lk;
    const float* wg = W + (size_t)(bo + lm) * C_ + lk;
    for (int k0 = 0; k0 < C_; k0 += GTK) {
        float4 a4 = *(const float4*)(xg + k0);
        float4 b4 = *(const float4*)(wg + k0);
        As[lk + 0][lm] = a4.x; As[lk + 1][lm] = a4.y;
        As[lk + 2][lm] = a4.z; As[lk + 3][lm] = a4.w;
        Bs[lk + 0][lm] = b4.x; Bs[lk + 1][lm] = b4.y;
        Bs[lk + 2][lm] = b4.z; Bs[lk + 3][lm] = b4.w;
        __syncthreads();
        #pragma unroll
        for (int kk = 0; kk < GTK; ++kk) {
            float4 av = *(const float4*)(&As[kk][tm]);
            float4 bv = *(const float4*)(&Bs[kk][tn]);
            float a[4] = {av.x, av.y, av.z, av.w};
            float b[4] = {bv.x, bv.y, bv.z, bv.w};
            #pragma unroll
            for (int i = 0; i < 4; ++i)
                #pragma unroll
                for (int j = 0; j < 4; ++j)
                    acc[i][j] += a[i] * b[j];
        }
        __syncthreads();
    }
    #pragma unroll
    for (int i = 0; i < 4; ++i) {
        #pragma unroll
        for (int j = 0; j < 4; ++j) {
            const int m = bm + tm + i;
            const int o = bo + tn + j;
            float val = acc[i][j] + qkv_b[o] * bias_mask[o];
            const int s = o >> 10;
            const int h = (o >> 6) & (H_ - 1);
            const int d = o & (D_ - 1);
            const int b = m >> 11;
            const int n = m & (N_ - 1);
            float* dst = (s == 0) ? Qb : (s == 1) ? Kb : Vb;
            dst[(((size_t)(b * H_ + h)) * N_ + n) * D_ + d] = val;
        }
    }
}

__global__ __launch_bounds__(256) void proj_gemm_kernel(
    const float* __restrict__ A,        // [8192, 1024]  (attn out, [B,N,C])
    const float* __restrict__ W,        // [1024, 1024]
    const float* __restrict__ proj_b,   // [1024]
    float* __restrict__ Out)            // [8192, 1024]
{
    __shared__ float As[GTK][GTM + 4];
    __shared__ float Bs[GTK][GTN + 4];
    const int bm = blockIdx.x * GTM;
    const int bo = blockIdx.y * GTN;
    const int tid = threadIdx.x;
    const int lm = tid >> 2;
    const int lk = (tid & 3) << 2;
    const int tm = (tid >> 4) << 2;
    const int tn = (tid & 15) << 2;
    float acc[4][4] = {};
    const float* ag = A + (size_t)(bm + lm) * C_ + lk;
    const float* wg = W + (size_t)(bo + lm) * C_ + lk;
    for (int k0 = 0; k0 < C_; k0 += GTK) {
        float4 a4 = *(const float4*)(ag + k0);
        float4 b4 = *(const float4*)(wg + k0);
        As[lk + 0][lm] = a4.x; As[lk + 1][lm] = a4.y;
        As[lk + 2][lm] = a4.z; As[lk + 3][lm] = a4.w;
        Bs[lk + 0][lm] = b4.x; Bs[lk + 1][lm] = b4.y;
        Bs[lk + 2][lm] = b4.z; Bs[lk + 3][lm] = b4.w;
        __syncthreads();
        #pragma unroll
        for (int kk = 0; kk < GTK; ++kk) {
            float4 av = *(const float4*)(&As[kk][tm]);
            float4 bv = *(const float4*)(&Bs[kk][tn]);
            float a[4] = {av.x, av.y, av.z, av.w};
            float b[4] = {bv.x, bv.y, bv.z, bv.w};
            #pragma unroll
            for (int i = 0; i < 4; ++i)
                #pragma unroll
                for (int j = 0; j < 4; ++j)
                    acc[i][j] += a[i] * b[j];
        }
        __syncthreads();
    }
    #pragma unroll
    for (int i = 0; i < 4; ++i) {
        #pragma unroll
        for (int j = 0; j < 4; ++j) {
            const int m = bm + tm + i;
            const int o = bo + tn + j;
            Out[(size_t)m * C_ + o] = acc[i][j] + proj_b[o];
        }
    }
}

// ---------------- flash attention, f32 vector, 1 thread = 1 query row ----------------
__global__ __launch_bounds__(256, 2) void attn_kernel(
    const float* __restrict__ Q,   // [B*H, N, D]
    const float* __restrict__ K,
    const float* __restrict__ V,
    float* __restrict__ O)         // [B, N, C]
{
    const int bh = blockIdx.y;                       // b*H + h
    const int n  = blockIdx.x * 256 + threadIdx.x;   // query row
    const size_t base = (size_t)bh * N_ * D_;

    const float4* q4 = (const float4*)(Q + base + (size_t)n * D_);
    float4 qr[16];
    #pragma unroll
    for (int j = 0; j < 16; ++j) {
        float4 t = q4[j];
        t.x *= SCALE_; t.y *= SCALE_; t.z *= SCALE_; t.w *= SCALE_;
        qr[j] = t;
    }
    float4 o4[16] = {};
    float mmax = -1e30f;
    float l = 0.f;

    const float4* Kr = (const float4*)(K + base);
    const float4* Vr = (const float4*)(V + base);

    for (int kk = 0; kk < N_; ++kk) {
        const float4* krow = Kr + (size_t)kk * 16;
        float s = 0.f;
        #pragma unroll
        for (int j = 0; j < 16; ++j) {
            const float4 kv = krow[j];
            s += qr[j].x * kv.x + qr[j].y * kv.y + qr[j].z * kv.z + qr[j].w * kv.w;
        }
        if (s > mmax) {
            const float corr = __expf(mmax - s);
            l *= corr;
            #pragma unroll
            for (int j = 0; j < 16; ++j) {
                o4[j].x *= corr; o4[j].y *= corr; o4[j].z *= corr; o4[j].w *= corr;
            }
            mmax = s;
        }
        const float p = __expf(s - mmax);
        l += p;
        const float4* vrow = Vr + (size_t)kk * 16;
        #pragma unroll
        for (int j = 0; j < 16; ++j) {
            const float4 vv = vrow[j];
            o4[j].x += p * vv.x; o4[j].y += p * vv.y;
            o4[j].z += p * vv.z; o4[j].w += p * vv.w;
        }
    }
    const float inv = 1.f / l;
    const int b = bh >> 4;
    const int h = bh & (H_ - 1);
    float4* out = (float4*)(O + ((size_t)(b * N_ + n)) * C_ + h * D_);
    #pragma unroll
    for (int j = 0; j < 16; ++j) {
        float4 r = o4[j];
        r.x *= inv; r.y *= inv; r.z *= inv; r.w *= inv;
        out[j] = r;
    }
}

extern "C" void kernel_launch(void* const* d_in, const int* in_sizes, int n_in,
                              void* d_out, int out_size, void* d_ws, size_t ws_size,
                              hipStream_t stream) {
    const float* x         = (const float*)d_in[0];
    const float* qkv_w     = (const float*)d_in[1];
    const float* qkv_b     = (const float*)d_in[2];
    const float* bias_mask = (const float*)d_in[3];
    const float* proj_w    = (const float*)d_in[4];
    const float* proj_b    = (const float*)d_in[5];
    float* out = (float*)d_out;

    const size_t NE = (size_t)B_ * H_ * N_ * D_;   // 8388608 elems
    float* Qb = (float*)d_ws;
    float* Kb = Qb + NE;
    float* Vb = Kb + NE;
    float* AO = Vb + NE;   // total 128 MiB of f32 workspace

    dim3 blk(256);
    qkv_gemm_kernel<<<dim3((B_ * N_) / GTM, (3 * C_) / GTN), blk, 0, stream>>>(
        x, qkv_w, qkv_b, bias_mask, Qb, Kb, Vb);
    attn_kernel<<<dim3(N_ / 256, B_ * H_), blk, 0, stream>>>(Qb, Kb, Vb, AO);
    proj_gemm_kernel<<<dim3((B_ * N_) / GTM, C_ / GTN), blk, 0, stream>>>(
        AO, proj_w, proj_b, out);
}

// Round 2
// 1383.497 us; speedup vs baseline: 3.6415x; 3.6415x over previous
//
#include <hip/hip_runtime.h>
#include <hip/hip_bf16.h>

#define B_ 4
#define N_ 2048
#define C_ 1024
#define H_ 16
#define D_ 64
#define SCALE_ 0.125f

typedef __attribute__((ext_vector_type(8))) short bf16x8;
typedef __attribute__((ext_vector_type(4))) float f32x4;
#define MFMA16(a, b, c) __builtin_amdgcn_mfma_f32_16x16x32_bf16(a, b, c, 0, 0, 0)

__device__ inline short f2bf(float f) {
    union { float f; unsigned u; } c; c.f = f;
    unsigned r = c.u + 0x7FFF + ((c.u >> 16) & 1);   // RNE
    return (short)(r >> 16);
}

// ---------------- tiled f32 GEMM: out[m][o] = sum_k A[m][k] * W[o][k] ----------------
#define GTM 64
#define GTN 64
#define GTK 16

__global__ __launch_bounds__(256) void qkv_gemm_kernel(
    const float* __restrict__ X,        // [8192, 1024]
    const float* __restrict__ W,        // [3072, 1024]
    const float* __restrict__ qkv_b,    // [3072]
    const float* __restrict__ bias_mask,// [3072]
    short* __restrict__ Qbf,            // [BH][N][D] bf16, pre-scaled
    short* __restrict__ Kbf,            // [BH][N][D] bf16
    short* __restrict__ Vt)             // [BH][D][N] bf16 (transposed)
{
    __shared__ float As[GTK][GTM + 4];
    __shared__ float Bs[GTK][GTN + 4];
    const int bm = blockIdx.x * GTM;
    const int bo = blockIdx.y * GTN;
    const int tid = threadIdx.x;
    const int lm = tid >> 2;          // 0..63
    const int lk = (tid & 3) << 2;    // 0,4,8,12
    const int tm = (tid >> 4) << 2;   // 0..60
    const int tn = (tid & 15) << 2;   // 0..60
    float acc[4][4] = {};
    const float* xg = X + (size_t)(bm + lm) * C_ + lk;
    const float* wg = W + (size_t)(bo + lm) * C_ + lk;
    for (int k0 = 0; k0 < C_; k0 += GTK) {
        float4 a4 = *(const float4*)(xg + k0);
        float4 b4 = *(const float4*)(wg + k0);
        As[lk + 0][lm] = a4.x; As[lk + 1][lm] = a4.y;
        As[lk + 2][lm] = a4.z; As[lk + 3][lm] = a4.w;
        Bs[lk + 0][lm] = b4.x; Bs[lk + 1][lm] = b4.y;
        Bs[lk + 2][lm] = b4.z; Bs[lk + 3][lm] = b4.w;
        __syncthreads();
        #pragma unroll
        for (int kk = 0; kk < GTK; ++kk) {
            float4 av = *(const float4*)(&As[kk][tm]);
            float4 bv = *(const float4*)(&Bs[kk][tn]);
            float a[4] = {av.x, av.y, av.z, av.w};
            float b[4] = {bv.x, bv.y, bv.z, bv.w};
            #pragma unroll
            for (int i = 0; i < 4; ++i)
                #pragma unroll
                for (int j = 0; j < 4; ++j)
                    acc[i][j] += a[i] * b[j];
        }
        __syncthreads();
    }
    #pragma unroll
    for (int i = 0; i < 4; ++i) {
        #pragma unroll
        for (int j = 0; j < 4; ++j) {
            const int m = bm + tm + i;
            const int o = bo + tn + j;
            float val = acc[i][j] + qkv_b[o] * bias_mask[o];
            const int s = o >> 10;
            const int h = (o >> 6) & (H_ - 1);
            const int d = o & (D_ - 1);
            const int b = m >> 11;
            const int n = m & (N_ - 1);
            const int bh = b * H_ + h;
            if (s == 0) {
                Qbf[((size_t)bh * N_ + n) * D_ + d] = f2bf(val * SCALE_);
            } else if (s == 1) {
                Kbf[((size_t)bh * N_ + n) * D_ + d] = f2bf(val);
            } else {
                Vt[((size_t)bh * D_ + d) * N_ + n] = f2bf(val);
            }
        }
    }
}

__global__ __launch_bounds__(256) void proj_gemm_kernel(
    const float* __restrict__ A,        // [8192, 1024]  (attn out, [B,N,C])
    const float* __restrict__ W,        // [1024, 1024]
    const float* __restrict__ proj_b,   // [1024]
    float* __restrict__ Out)            // [8192, 1024]
{
    __shared__ float As[GTK][GTM + 4];
    __shared__ float Bs[GTK][GTN + 4];
    const int bm = blockIdx.x * GTM;
    const int bo = blockIdx.y * GTN;
    const int tid = threadIdx.x;
    const int lm = tid >> 2;
    const int lk = (tid & 3) << 2;
    const int tm = (tid >> 4) << 2;
    const int tn = (tid & 15) << 2;
    float acc[4][4] = {};
    const float* ag = A + (size_t)(bm + lm) * C_ + lk;
    const float* wg = W + (size_t)(bo + lm) * C_ + lk;
    for (int k0 = 0; k0 < C_; k0 += GTK) {
        float4 a4 = *(const float4*)(ag + k0);
        float4 b4 = *(const float4*)(wg + k0);
        As[lk + 0][lm] = a4.x; As[lk + 1][lm] = a4.y;
        As[lk + 2][lm] = a4.z; As[lk + 3][lm] = a4.w;
        Bs[lk + 0][lm] = b4.x; Bs[lk + 1][lm] = b4.y;
        Bs[lk + 2][lm] = b4.z; Bs[lk + 3][lm] = b4.w;
        __syncthreads();
        #pragma unroll
        for (int kk = 0; kk < GTK; ++kk) {
            float4 av = *(const float4*)(&As[kk][tm]);
            float4 bv = *(const float4*)(&Bs[kk][tn]);
            float a[4] = {av.x, av.y, av.z, av.w};
            float b[4] = {bv.x, bv.y, bv.z, bv.w};
            #pragma unroll
            for (int i = 0; i < 4; ++i)
                #pragma unroll
                for (int j = 0; j < 4; ++j)
                    acc[i][j] += a[i] * b[j];
        }
        __syncthreads();
    }
    #pragma unroll
    for (int i = 0; i < 4; ++i) {
        #pragma unroll
        for (int j = 0; j < 4; ++j) {
            const int m = bm + tm + i;
            const int o = bo + tn + j;
            Out[(size_t)m * C_ + o] = acc[i][j] + proj_b[o];
        }
    }
}

// ---------------- MFMA bf16 flash attention ----------------
// Per wave: 16 q-rows. kv chunks of 32. Q pre-scaled bf16, V pre-transposed.
// S = mfma(A=Q, B=Kfrag): D-layout col = lane&15 = kv, row = (lane>>4)*4+r = q.
__global__ __launch_bounds__(256) void attn_mfma_kernel(
    const short* __restrict__ Qb,  // [BH][N][D] bf16 (scaled)
    const short* __restrict__ Kb,  // [BH][N][D] bf16
    const short* __restrict__ Vt,  // [BH][D][N] bf16
    float* __restrict__ AO)        // [B][N][C] f32
{
    __shared__ short Plds[4][16 * 40];   // per-wave P tile [q][kv], row stride 40 (80B, 16B-aligned)
    const int tid  = threadIdx.x;
    const int wave = tid >> 6;
    const int lane = tid & 63;
    const int lo   = lane & 15;
    const int grp  = lane >> 4;
    const int bh   = blockIdx.y;
    const int q0   = blockIdx.x * 64 + wave * 16;

    const size_t base = (size_t)bh * N_ * D_;

    // Q A-frags: lane holds row q=lo, k=d=grp*8+e  (two 32-wide d halves)
    const short* qrow = Qb + base + (size_t)(q0 + lo) * D_ + grp * 8;
    const bf16x8 qf0 = *(const bf16x8*)(qrow);
    const bf16x8 qf1 = *(const bf16x8*)(qrow + 32);

    f32x4 o[4];
    #pragma unroll
    for (int db = 0; db < 4; ++db) o[db] = f32x4{0.f, 0.f, 0.f, 0.f};
    float m[4]    = {-1e30f, -1e30f, -1e30f, -1e30f};
    float lsum[4] = {0.f, 0.f, 0.f, 0.f};

    const short* Kp = Kb + base;
    const short* Vp = Vt + base;
    short* pw = &Plds[wave][0];
    const f32x4 zero = {0.f, 0.f, 0.f, 0.f};

    for (int kv0 = 0; kv0 < N_; kv0 += 32) {
        // K B-frags: lane holds col kv=lo, k=d=grp*8+e
        const short* kr0 = Kp + (size_t)(kv0 + lo) * D_ + grp * 8;
        const short* kr1 = Kp + (size_t)(kv0 + 16 + lo) * D_ + grp * 8;
        const bf16x8 kf00 = *(const bf16x8*)(kr0);
        const bf16x8 kf01 = *(const bf16x8*)(kr0 + 32);
        const bf16x8 kf10 = *(const bf16x8*)(kr1);
        const bf16x8 kf11 = *(const bf16x8*)(kr1 + 32);
        // V^T B-frags: lane holds col d=db*16+lo, k=kv=grp*8+e
        bf16x8 vf[4];
        #pragma unroll
        for (int db = 0; db < 4; ++db)
            vf[db] = *(const bf16x8*)(Vp + (size_t)(db * 16 + lo) * N_ + kv0 + grp * 8);

        f32x4 s0 = MFMA16(qf0, kf00, zero);
        s0 = MFMA16(qf1, kf01, s0);
        f32x4 s1 = MFMA16(qf0, kf10, zero);
        s1 = MFMA16(qf1, kf11, s1);

        // online softmax: rows q=grp*4+r; reduce over kv = 16 lanes of this group
        float tmax[4];
        #pragma unroll
        for (int r = 0; r < 4; ++r) tmax[r] = fmaxf(s0[r], s1[r]);
        #pragma unroll
        for (int mask = 1; mask < 16; mask <<= 1) {
            #pragma unroll
            for (int r = 0; r < 4; ++r)
                tmax[r] = fmaxf(tmax[r], __shfl_xor(tmax[r], mask, 64));
        }
        float corr[4], p0[4], p1[4], rs[4];
        #pragma unroll
        for (int r = 0; r < 4; ++r) {
            const float mn = fmaxf(m[r], tmax[r]);
            corr[r] = __expf(m[r] - mn);
            m[r] = mn;
            p0[r] = __expf(s0[r] - mn);
            p1[r] = __expf(s1[r] - mn);
            rs[r] = p0[r] + p1[r];
        }
        #pragma unroll
        for (int mask = 1; mask < 16; mask <<= 1) {
            #pragma unroll
            for (int r = 0; r < 4; ++r)
                rs[r] += __shfl_xor(rs[r], mask, 64);
        }
        #pragma unroll
        for (int r = 0; r < 4; ++r) lsum[r] = lsum[r] * corr[r] + rs[r];
        #pragma unroll
        for (int db = 0; db < 4; ++db)
            #pragma unroll
            for (int r = 0; r < 4; ++r) o[db][r] *= corr[r];

        // P -> LDS ([q][kv], rows q=grp*4+r, cols lo and lo+16)
        #pragma unroll
        for (int r = 0; r < 4; ++r) {
            const int q = grp * 4 + r;
            pw[q * 40 + lo]      = f2bf(p0[r]);
            pw[q * 40 + 16 + lo] = f2bf(p1[r]);
        }
        // P A-frag: lane reads row q=lo, kv=grp*8+e (contiguous 16B)
        const bf16x8 pf = *(const bf16x8*)(pw + lo * 40 + grp * 8);
        #pragma unroll
        for (int db = 0; db < 4; ++db)
            o[db] = MFMA16(pf, vf[db], o[db]);
    }

    // epilogue: normalize + write f32 to AO[b][n][h*64 + d]
    const int b = bh >> 4;
    const int h = bh & (H_ - 1);
    float inv[4];
    #pragma unroll
    for (int r = 0; r < 4; ++r) inv[r] = 1.f / lsum[r];
    #pragma unroll
    for (int db = 0; db < 4; ++db) {
        #pragma unroll
        for (int r = 0; r < 4; ++r) {
            const int n = q0 + grp * 4 + r;
            AO[((size_t)(b * N_ + n)) * C_ + h * D_ + db * 16 + lo] = o[db][r] * inv[r];
        }
    }
}

extern "C" void kernel_launch(void* const* d_in, const int* in_sizes, int n_in,
                              void* d_out, int out_size, void* d_ws, size_t ws_size,
                              hipStream_t stream) {
    const float* x         = (const float*)d_in[0];
    const float* qkv_w     = (const float*)d_in[1];
    const float* qkv_b     = (const float*)d_in[2];
    const float* bias_mask = (const float*)d_in[3];
    const float* proj_w    = (const float*)d_in[4];
    const float* proj_b    = (const float*)d_in[5];
    float* out = (float*)d_out;

    const size_t NE = (size_t)B_ * H_ * N_ * D_;   // 8388608 elems
    short* Qbf = (short*)d_ws;
    short* Kbf = Qbf + NE;
    short* Vt  = Kbf + NE;
    float* AO  = (float*)(Vt + NE);   // 3*16.8MB bf16 + 32MB f32

    dim3 blk(256);
    qkv_gemm_kernel<<<dim3((B_ * N_) / GTM, (3 * C_) / GTN), blk, 0, stream>>>(
        x, qkv_w, qkv_b, bias_mask, Qbf, Kbf, Vt);
    attn_mfma_kernel<<<dim3(N_ / 64, B_ * H_), blk, 0, stream>>>(Qbf, Kbf, Vt, AO);
    proj_gemm_kernel<<<dim3((B_ * N_) / GTM, C_ / GTN), blk, 0, stream>>>(
        AO, proj_w, proj_b, out);
}

// Round 3
// 573.168 us; speedup vs baseline: 8.7896x; 2.4138x over previous
//
#include <hip/hip_runtime.h>
#include <hip/hip_bf16.h>

#define B_ 4
#define N_ 2048
#define C_ 1024
#define H_ 16
#define D_ 64
#define SCALE_ 0.125f

typedef _Float16 f16;
typedef __attribute__((ext_vector_type(8))) _Float16 f16x8;
typedef __attribute__((ext_vector_type(4))) _Float16 f16x4;
typedef __attribute__((ext_vector_type(4))) float f32x4;
#define MFMA16(a, b, c) __builtin_amdgcn_mfma_f32_16x16x32_f16(a, b, c, 0, 0, 0)

__device__ inline void gload_lds16(const f16* g, f16* l) {
    __builtin_amdgcn_global_load_lds(
        (const __attribute__((address_space(1))) void*)g,
        (__attribute__((address_space(3))) void*)l, 16, 0, 0);
}

// ---------------- f32 -> f16 convert (x, qkv_w, proj_w) ----------------
#define NX_ 8388608u
#define NW1_ 3145728u
#define NW2_ 1048576u

__global__ __launch_bounds__(256) void convert_kernel(
    const float* __restrict__ x, const float* __restrict__ w1, const float* __restrict__ w2,
    f16* __restrict__ xo, f16* __restrict__ w1o, f16* __restrict__ w2o)
{
    const unsigned q = blockIdx.x * 256 + threadIdx.x;
    const unsigned i = q << 2;
    const float* src;
    f16* dst;
    if (i < NX_)              { src = x  + i;               dst = xo  + i; }
    else if (i < NX_ + NW1_)  { src = w1 + (i - NX_);       dst = w1o + (i - NX_); }
    else                      { src = w2 + (i - NX_ - NW1_); dst = w2o + (i - NX_ - NW1_); }
    const float4 v = *(const float4*)src;
    f16x4 h;
    h[0] = (f16)v.x; h[1] = (f16)v.y; h[2] = (f16)v.z; h[3] = (f16)v.w;
    *(f16x4*)dst = h;
}

// ---------------- f16 MFMA GEMM: C[m][o] = sum_k A[m][k] * W[o][k] ----------------
// 128x128 tile, BK=64, 4 waves (2x2), global_load_lds w16, XOR-swizzled LDS.
// Swizzle: LDS slot (row, colgrp16B) holds source k-group (colgrp ^ (row&7)).

__global__ __launch_bounds__(256) void qkv_gemm_f16(
    const f16* __restrict__ Xh,        // [8192][1024]
    const f16* __restrict__ Wh,        // [3072][1024]
    const float* __restrict__ qkv_b,
    const float* __restrict__ bias_mask,
    f16* __restrict__ Qh,              // [BH][N][D] (pre-scaled)
    f16* __restrict__ Kh,              // [BH][N][D]
    f16* __restrict__ Vt)              // [BH][D][N]
{
    __shared__ f16 As[128 * 64];
    __shared__ f16 Bs[128 * 64];
    const int tid  = threadIdx.x;
    const int bm   = blockIdx.x * 128;
    const int bo   = blockIdx.y * 128;
    const int lane = tid & 63, lo = lane & 15, grp = lane >> 4;
    const int wave = tid >> 6, wr = wave >> 1, wc = wave & 1;
    const int sr = tid >> 3, cg = tid & 7;           // staging row (0..31), col-group
    const int scol = (cg ^ (sr & 7)) << 3;           // inverse-swizzled source col (f16 elems)

    f32x4 acc[4][4];
    #pragma unroll
    for (int m = 0; m < 4; ++m)
        #pragma unroll
        for (int n = 0; n < 4; ++n) acc[m][n] = f32x4{0.f, 0.f, 0.f, 0.f};

    for (int k0 = 0; k0 < 1024; k0 += 64) {
        #pragma unroll
        for (int i = 0; i < 4; ++i) {
            const int tr = i * 32 + sr;
            gload_lds16(Xh + (size_t)(bm + tr) * 1024 + k0 + scol, As + (i * 2048 + tid * 8));
            gload_lds16(Wh + (size_t)(bo + tr) * 1024 + k0 + scol, Bs + (i * 2048 + tid * 8));
        }
        __syncthreads();
        #pragma unroll
        for (int kh = 0; kh < 2; ++kh) {
            f16x8 af[4], bfr[4];
            #pragma unroll
            for (int m = 0; m < 4; ++m) {
                const int row = wr * 64 + m * 16 + lo;
                af[m] = *(const f16x8*)(As + row * 64 + ((((kh << 2) + grp) << 3) ^ ((row & 7) << 3)));
            }
            #pragma unroll
            for (int n = 0; n < 4; ++n) {
                const int row = wc * 64 + n * 16 + lo;
                bfr[n] = *(const f16x8*)(Bs + row * 64 + ((((kh << 2) + grp) << 3) ^ ((row & 7) << 3)));
            }
            #pragma unroll
            for (int m = 0; m < 4; ++m)
                #pragma unroll
                for (int n = 0; n < 4; ++n)
                    acc[m][n] = MFMA16(af[m], bfr[n], acc[m][n]);
        }
        __syncthreads();
    }
    // epilogue: scatter to Q (scaled), K, V^T
    #pragma unroll
    for (int ni = 0; ni < 4; ++ni) {
        const int o = bo + wc * 64 + ni * 16 + lo;
        const float bias = qkv_b[o] * bias_mask[o];
        const int s = o >> 10, h = (o >> 6) & 15, d = o & 63;
        #pragma unroll
        for (int mi = 0; mi < 4; ++mi) {
            #pragma unroll
            for (int r = 0; r < 4; ++r) {
                const int m = bm + wr * 64 + mi * 16 + grp * 4 + r;
                const int b = m >> 11, n = m & (N_ - 1);
                const int bh = b * H_ + h;
                const float val = acc[mi][ni][r] + bias;
                if (s == 0)      Qh[((size_t)bh * N_ + n) * D_ + d] = (f16)(val * SCALE_);
                else if (s == 1) Kh[((size_t)bh * N_ + n) * D_ + d] = (f16)val;
                else             Vt[((size_t)bh * D_ + d) * N_ + n] = (f16)val;
            }
        }
    }
}

__global__ __launch_bounds__(256) void proj_gemm_f16(
    const f16* __restrict__ Ah,        // [8192][1024] attn out
    const f16* __restrict__ Wh,        // [1024][1024]
    const float* __restrict__ proj_b,
    float* __restrict__ Out)           // [8192][1024] f32
{
    __shared__ f16 As[128 * 64];
    __shared__ f16 Bs[128 * 64];
    const int tid  = threadIdx.x;
    const int bm   = blockIdx.x * 128;
    const int bo   = blockIdx.y * 128;
    const int lane = tid & 63, lo = lane & 15, grp = lane >> 4;
    const int wave = tid >> 6, wr = wave >> 1, wc = wave & 1;
    const int sr = tid >> 3, cg = tid & 7;
    const int scol = (cg ^ (sr & 7)) << 3;

    f32x4 acc[4][4];
    #pragma unroll
    for (int m = 0; m < 4; ++m)
        #pragma unroll
        for (int n = 0; n < 4; ++n) acc[m][n] = f32x4{0.f, 0.f, 0.f, 0.f};

    for (int k0 = 0; k0 < 1024; k0 += 64) {
        #pragma unroll
        for (int i = 0; i < 4; ++i) {
            const int tr = i * 32 + sr;
            gload_lds16(Ah + (size_t)(bm + tr) * 1024 + k0 + scol, As + (i * 2048 + tid * 8));
            gload_lds16(Wh + (size_t)(bo + tr) * 1024 + k0 + scol, Bs + (i * 2048 + tid * 8));
        }
        __syncthreads();
        #pragma unroll
        for (int kh = 0; kh < 2; ++kh) {
            f16x8 af[4], bfr[4];
            #pragma unroll
            for (int m = 0; m < 4; ++m) {
                const int row = wr * 64 + m * 16 + lo;
                af[m] = *(const f16x8*)(As + row * 64 + ((((kh << 2) + grp) << 3) ^ ((row & 7) << 3)));
            }
            #pragma unroll
            for (int n = 0; n < 4; ++n) {
                const int row = wc * 64 + n * 16 + lo;
                bfr[n] = *(const f16x8*)(Bs + row * 64 + ((((kh << 2) + grp) << 3) ^ ((row & 7) << 3)));
            }
            #pragma unroll
            for (int m = 0; m < 4; ++m)
                #pragma unroll
                for (int n = 0; n < 4; ++n)
                    acc[m][n] = MFMA16(af[m], bfr[n], acc[m][n]);
        }
        __syncthreads();
    }
    #pragma unroll
    for (int ni = 0; ni < 4; ++ni) {
        const int o = bo + wc * 64 + ni * 16 + lo;
        const float pb = proj_b[o];
        #pragma unroll
        for (int mi = 0; mi < 4; ++mi) {
            #pragma unroll
            for (int r = 0; r < 4; ++r) {
                const int m = bm + wr * 64 + mi * 16 + grp * 4 + r;
                Out[(size_t)m * C_ + o] = acc[mi][ni][r] + pb;
            }
        }
    }
}

// ---------------- MFMA f16 flash attention (16 q-rows/wave, kv chunks of 32) ----------------
__global__ __launch_bounds__(256) void attn_mfma_kernel(
    const f16* __restrict__ Qb,  // [BH][N][D] (scaled)
    const f16* __restrict__ Kb,  // [BH][N][D]
    const f16* __restrict__ Vt,  // [BH][D][N]
    f16* __restrict__ AO)        // [B][N][C] f16
{
    __shared__ f16 Plds[4][16 * 40];
    const int tid  = threadIdx.x;
    const int wave = tid >> 6;
    const int lane = tid & 63;
    const int lo   = lane & 15;
    const int grp  = lane >> 4;
    const int bh   = blockIdx.y;
    const int q0   = blockIdx.x * 64 + wave * 16;

    const size_t base = (size_t)bh * N_ * D_;

    const f16* qrow = Qb + base + (size_t)(q0 + lo) * D_ + grp * 8;
    const f16x8 qf0 = *(const f16x8*)(qrow);
    const f16x8 qf1 = *(const f16x8*)(qrow + 32);

    f32x4 o[4];
    #pragma unroll
    for (int db = 0; db < 4; ++db) o[db] = f32x4{0.f, 0.f, 0.f, 0.f};
    float m[4]    = {-1e30f, -1e30f, -1e30f, -1e30f};
    float lsum[4] = {0.f, 0.f, 0.f, 0.f};

    const f16* Kp = Kb + base;
    const f16* Vp = Vt + base;
    f16* pw = &Plds[wave][0];
    const f32x4 zero = {0.f, 0.f, 0.f, 0.f};

    for (int kv0 = 0; kv0 < N_; kv0 += 32) {
        const f16* kr0 = Kp + (size_t)(kv0 + lo) * D_ + grp * 8;
        const f16* kr1 = Kp + (size_t)(kv0 + 16 + lo) * D_ + grp * 8;
        const f16x8 kf00 = *(const f16x8*)(kr0);
        const f16x8 kf01 = *(const f16x8*)(kr0 + 32);
        const f16x8 kf10 = *(const f16x8*)(kr1);
        const f16x8 kf11 = *(const f16x8*)(kr1 + 32);
        f16x8 vf[4];
        #pragma unroll
        for (int db = 0; db < 4; ++db)
            vf[db] = *(const f16x8*)(Vp + (size_t)(db * 16 + lo) * N_ + kv0 + grp * 8);

        f32x4 s0 = MFMA16(qf0, kf00, zero);
        s0 = MFMA16(qf1, kf01, s0);
        f32x4 s1 = MFMA16(qf0, kf10, zero);
        s1 = MFMA16(qf1, kf11, s1);

        float tmax[4];
        #pragma unroll
        for (int r = 0; r < 4; ++r) tmax[r] = fmaxf(s0[r], s1[r]);
        #pragma unroll
        for (int mask = 1; mask < 16; mask <<= 1) {
            #pragma unroll
            for (int r = 0; r < 4; ++r)
                tmax[r] = fmaxf(tmax[r], __shfl_xor(tmax[r], mask, 64));
        }
        float corr[4], p0[4], p1[4], rs[4];
        #pragma unroll
        for (int r = 0; r < 4; ++r) {
            const float mn = fmaxf(m[r], tmax[r]);
            corr[r] = __expf(m[r] - mn);
            m[r] = mn;
            p0[r] = __expf(s0[r] - mn);
            p1[r] = __expf(s1[r] - mn);
            rs[r] = p0[r] + p1[r];
        }
        #pragma unroll
        for (int mask = 1; mask < 16; mask <<= 1) {
            #pragma unroll
            for (int r = 0; r < 4; ++r)
                rs[r] += __shfl_xor(rs[r], mask, 64);
        }
        #pragma unroll
        for (int r = 0; r < 4; ++r) lsum[r] = lsum[r] * corr[r] + rs[r];
        #pragma unroll
        for (int db = 0; db < 4; ++db)
            #pragma unroll
            for (int r = 0; r < 4; ++r) o[db][r] *= corr[r];

        #pragma unroll
        for (int r = 0; r < 4; ++r) {
            const int q = grp * 4 + r;
            pw[q * 40 + lo]      = (f16)p0[r];
            pw[q * 40 + 16 + lo] = (f16)p1[r];
        }
        const f16x8 pf = *(const f16x8*)(pw + lo * 40 + grp * 8);
        #pragma unroll
        for (int db = 0; db < 4; ++db)
            o[db] = MFMA16(pf, vf[db], o[db]);
    }

    const int b = bh >> 4;
    const int h = bh & (H_ - 1);
    float inv[4];
    #pragma unroll
    for (int r = 0; r < 4; ++r) inv[r] = 1.f / lsum[r];
    #pragma unroll
    for (int db = 0; db < 4; ++db) {
        #pragma unroll
        for (int r = 0; r < 4; ++r) {
            const int n = q0 + grp * 4 + r;
            AO[((size_t)(b * N_ + n)) * C_ + h * D_ + db * 16 + lo] = (f16)(o[db][r] * inv[r]);
        }
    }
}

extern "C" void kernel_launch(void* const* d_in, const int* in_sizes, int n_in,
                              void* d_out, int out_size, void* d_ws, size_t ws_size,
                              hipStream_t stream) {
    const float* x         = (const float*)d_in[0];
    const float* qkv_w     = (const float*)d_in[1];
    const float* qkv_b     = (const float*)d_in[2];
    const float* bias_mask = (const float*)d_in[3];
    const float* proj_w    = (const float*)d_in[4];
    const float* proj_b    = (const float*)d_in[5];
    float* out = (float*)d_out;

    const size_t NE = (size_t)B_ * H_ * N_ * D_;   // 8388608
    f16* Xh = (f16*)d_ws;
    f16* Wh = Xh + NE;              // 3145728
    f16* Ph = Wh + NW1_;            // 1048576
    f16* Qh = Ph + NW2_;
    f16* Kh = Qh + NE;
    f16* Vt = Kh + NE;
    f16* AOh = Vt + NE;             // total ~82 MB

    dim3 blk(256);
    convert_kernel<<<12288, blk, 0, stream>>>(x, qkv_w, proj_w, Xh, Wh, Ph);
    qkv_gemm_f16<<<dim3(64, 24), blk, 0, stream>>>(Xh, Wh, qkv_b, bias_mask, Qh, Kh, Vt);
    attn_mfma_kernel<<<dim3(N_ / 64, B_ * H_), blk, 0, stream>>>(Qh, Kh, Vt, AOh);
    proj_gemm_f16<<<dim3(64, 8), blk, 0, stream>>>(AOh, Ph, proj_b, out);
}

// Round 10
// 358.785 us; speedup vs baseline: 14.0417x; 1.5975x over previous
//
#include <hip/hip_runtime.h>
#include <hip/hip_bf16.h>

#define B_ 4
#define N_ 2048
#define C_ 1024
#define H_ 16
#define D_ 64
#define SCALE_ 0.125f

typedef _Float16 f16;
typedef __attribute__((ext_vector_type(8))) _Float16 f16x8;
typedef __attribute__((ext_vector_type(4))) _Float16 f16x4;
typedef __attribute__((ext_vector_type(4))) float f32x4;
typedef __attribute__((ext_vector_type(16))) float f32x16;
#define MFMA16(a, b, c) __builtin_amdgcn_mfma_f32_16x16x32_f16(a, b, c, 0, 0, 0)
#define MFMA32(a, b, c) __builtin_amdgcn_mfma_f32_32x32x16_f16(a, b, c, 0, 0, 0)

__device__ inline void gload_lds16(const f16* g, f16* l) {
    __builtin_amdgcn_global_load_lds(
        (const __attribute__((address_space(1))) void*)g,
        (__attribute__((address_space(3))) void*)l, 16, 0, 0);
}

// ---------------- f32 -> f16 convert (x, qkv_w, proj_w) ----------------
#define NX_ 8388608u
#define NW1_ 3145728u
#define NW2_ 1048576u

__global__ __launch_bounds__(256) void convert_kernel(
    const float* __restrict__ x, const float* __restrict__ w1, const float* __restrict__ w2,
    f16* __restrict__ xo, f16* __restrict__ w1o, f16* __restrict__ w2o)
{
    const unsigned q = blockIdx.x * 256 + threadIdx.x;
    const unsigned i = q << 2;
    const float* src;
    f16* dst;
    if (i < NX_)              { src = x  + i;               dst = xo  + i; }
    else if (i < NX_ + NW1_)  { src = w1 + (i - NX_);       dst = w1o + (i - NX_); }
    else                      { src = w2 + (i - NX_ - NW1_); dst = w2o + (i - NX_ - NW1_); }
    const float4 v = *(const float4*)src;
    f16x4 h;
    h[0] = (f16)v.x; h[1] = (f16)v.y; h[2] = (f16)v.z; h[3] = (f16)v.w;
    *(f16x4*)dst = h;
}

// ---------------- f16 MFMA GEMM: C[m][o] = sum_k A[m][k] * W[o][k] ----------------
__global__ __launch_bounds__(256) void qkv_gemm_f16(
    const f16* __restrict__ Xh,        // [8192][1024]
    const f16* __restrict__ Wh,        // [3072][1024]
    const float* __restrict__ qkv_b,
    const float* __restrict__ bias_mask,
    f16* __restrict__ Qh,              // [BH][N][D] (pre-scaled)
    f16* __restrict__ Kh,              // [BH][N][D]
    f16* __restrict__ Vt)              // [BH][D][N]
{
    __shared__ f16 As[128 * 64];
    __shared__ f16 Bs[128 * 64];
    const int tid  = threadIdx.x;
    const int bm   = blockIdx.x * 128;
    const int bo   = blockIdx.y * 128;
    const int lane = tid & 63, lo = lane & 15, grp = lane >> 4;
    const int wave = tid >> 6, wr = wave >> 1, wc = wave & 1;
    const int sr = tid >> 3, cg = tid & 7;
    const int scol = (cg ^ (sr & 7)) << 3;

    f32x4 acc[4][4];
    #pragma unroll
    for (int m = 0; m < 4; ++m)
        #pragma unroll
        for (int n = 0; n < 4; ++n) acc[m][n] = f32x4{0.f, 0.f, 0.f, 0.f};

    for (int k0 = 0; k0 < 1024; k0 += 64) {
        #pragma unroll
        for (int i = 0; i < 4; ++i) {
            const int tr = i * 32 + sr;
            gload_lds16(Xh + (size_t)(bm + tr) * 1024 + k0 + scol, As + (i * 2048 + tid * 8));
            gload_lds16(Wh + (size_t)(bo + tr) * 1024 + k0 + scol, Bs + (i * 2048 + tid * 8));
        }
        __syncthreads();
        #pragma unroll
        for (int kh = 0; kh < 2; ++kh) {
            f16x8 af[4], bfr[4];
            #pragma unroll
            for (int m = 0; m < 4; ++m) {
                const int row = wr * 64 + m * 16 + lo;
                af[m] = *(const f16x8*)(As + row * 64 + ((((kh << 2) + grp) << 3) ^ ((row & 7) << 3)));
            }
            #pragma unroll
            for (int n = 0; n < 4; ++n) {
                const int row = wc * 64 + n * 16 + lo;
                bfr[n] = *(const f16x8*)(Bs + row * 64 + ((((kh << 2) + grp) << 3) ^ ((row & 7) << 3)));
            }
            #pragma unroll
            for (int m = 0; m < 4; ++m)
                #pragma unroll
                for (int n = 0; n < 4; ++n)
                    acc[m][n] = MFMA16(af[m], bfr[n], acc[m][n]);
        }
        __syncthreads();
    }
    #pragma unroll
    for (int ni = 0; ni < 4; ++ni) {
        const int o = bo + wc * 64 + ni * 16 + lo;
        const float bias = qkv_b[o] * bias_mask[o];
        const int s = o >> 10, h = (o >> 6) & 15, d = o & 63;
        #pragma unroll
        for (int mi = 0; mi < 4; ++mi) {
            #pragma unroll
            for (int r = 0; r < 4; ++r) {
                const int m = bm + wr * 64 + mi * 16 + grp * 4 + r;
                const int b = m >> 11, n = m & (N_ - 1);
                const int bh = b * H_ + h;
                const float val = acc[mi][ni][r] + bias;
                if (s == 0)      Qh[((size_t)bh * N_ + n) * D_ + d] = (f16)(val * SCALE_);
                else if (s == 1) Kh[((size_t)bh * N_ + n) * D_ + d] = (f16)val;
                else             Vt[((size_t)bh * D_ + d) * N_ + n] = (f16)val;
            }
        }
    }
}

__global__ __launch_bounds__(256) void proj_gemm_f16(
    const f16* __restrict__ Ah,        // [8192][1024] attn out
    const f16* __restrict__ Wh,        // [1024][1024]
    const float* __restrict__ proj_b,
    float* __restrict__ Out)           // [8192][1024] f32
{
    __shared__ f16 As[128 * 64];
    __shared__ f16 Bs[128 * 64];
    const int tid  = threadIdx.x;
    const int bm   = blockIdx.x * 128;
    const int bo   = blockIdx.y * 128;
    const int lane = tid & 63, lo = lane & 15, grp = lane >> 4;
    const int wave = tid >> 6, wr = wave >> 1, wc = wave & 1;
    const int sr = tid >> 3, cg = tid & 7;
    const int scol = (cg ^ (sr & 7)) << 3;

    f32x4 acc[4][4];
    #pragma unroll
    for (int m = 0; m < 4; ++m)
        #pragma unroll
        for (int n = 0; n < 4; ++n) acc[m][n] = f32x4{0.f, 0.f, 0.f, 0.f};

    for (int k0 = 0; k0 < 1024; k0 += 64) {
        #pragma unroll
        for (int i = 0; i < 4; ++i) {
            const int tr = i * 32 + sr;
            gload_lds16(Ah + (size_t)(bm + tr) * 1024 + k0 + scol, As + (i * 2048 + tid * 8));
            gload_lds16(Wh + (size_t)(bo + tr) * 1024 + k0 + scol, Bs + (i * 2048 + tid * 8));
        }
        __syncthreads();
        #pragma unroll
        for (int kh = 0; kh < 2; ++kh) {
            f16x8 af[4], bfr[4];
            #pragma unroll
            for (int m = 0; m < 4; ++m) {
                const int row = wr * 64 + m * 16 + lo;
                af[m] = *(const f16x8*)(As + row * 64 + ((((kh << 2) + grp) << 3) ^ ((row & 7) << 3)));
            }
            #pragma unroll
            for (int n = 0; n < 4; ++n) {
                const int row = wc * 64 + n * 16 + lo;
                bfr[n] = *(const f16x8*)(Bs + row * 64 + ((((kh << 2) + grp) << 3) ^ ((row & 7) << 3)));
            }
            #pragma unroll
            for (int m = 0; m < 4; ++m)
                #pragma unroll
                for (int n = 0; n < 4; ++n)
                    acc[m][n] = MFMA16(af[m], bfr[n], acc[m][n]);
        }
        __syncthreads();
    }
    #pragma unroll
    for (int ni = 0; ni < 4; ++ni) {
        const int o = bo + wc * 64 + ni * 16 + lo;
        const float pb = proj_b[o];
        #pragma unroll
        for (int mi = 0; mi < 4; ++mi) {
            #pragma unroll
            for (int r = 0; r < 4; ++r) {
                const int m = bm + wr * 64 + mi * 16 + grp * 4 + r;
                Out[(size_t)m * C_ + o] = acc[mi][ni][r] + pb;
            }
        }
    }
}

// ---------------- swapped-QK^T 32x32 MFMA flash attention (no permlane) ----------------
// Per wave: 32 q-rows, kv chunks of 32.
// S^T = mfma32(A=K, B=Q): lane (lo,hi) reg r holds S[kv=(r&3)+8(r>>2)+4hi][q=lo]  [m74/m101]
// Cross-half reduce: __shfl_xor(...,32). P redistribution: wave-private LDS
// round-trip (write P[q][kv] packed pairs, read back b128 as PV B-frag) — the
// exact write-then-read-no-barrier pattern hardware-validated by the r3 kernel.
__global__ __launch_bounds__(256) void attn_fa3_kernel(
    const f16* __restrict__ Qb,  // [BH][N][D] (scaled)
    const f16* __restrict__ Kb,  // [BH][N][D]
    const f16* __restrict__ Vt,  // [BH][D][N]
    f16* __restrict__ AO)        // [B][N][C] f16
{
    __shared__ f16 Plds[4][32 * 36];   // per-wave P[q][kv], row stride 36 f16
    const int tid  = threadIdx.x;
    const int wave = tid >> 6;
    const int lane = tid & 63;
    const int lo   = lane & 31;
    const int hi   = lane >> 5;
    const int bh   = blockIdx.y;
    const int q0   = blockIdx.x * 128 + wave * 32;
    const size_t base = (size_t)bh * (N_ * D_);

    // Q B-frags (col=q=lo, k = dc*16 + hi*8 + e)
    f16x8 qf[4];
    #pragma unroll
    for (int dc = 0; dc < 4; ++dc)
        qf[dc] = *(const f16x8*)(Qb + base + (size_t)(q0 + lo) * D_ + dc * 16 + hi * 8);

    const f32x16 zero16 = {};
    f32x16 o0 = zero16, o1 = zero16;   // O^T: reg r = O[d=(dh*32)+(r&3)+8(r>>2)+4hi][q=lo]
    float m = -1e30f, lsum = 0.f;

    const f16* Kp = Kb + base;
    const f16* Vp = Vt + base;
    f16* pw = &Plds[wave][0];

    for (int kv0 = 0; kv0 < N_; kv0 += 32) {
        // K A-frags (row=kv=lo, k = d = dc*16 + hi*8 + e)
        const f16* kr = Kp + (size_t)(kv0 + lo) * D_ + hi * 8;
        const f16x8 kf0 = *(const f16x8*)(kr);
        const f16x8 kf1 = *(const f16x8*)(kr + 16);
        const f16x8 kf2 = *(const f16x8*)(kr + 32);
        const f16x8 kf3 = *(const f16x8*)(kr + 48);
        f32x16 s = MFMA32(kf0, qf[0], zero16);
        s = MFMA32(kf1, qf[1], s);
        s = MFMA32(kf2, qf[2], s);
        s = MFMA32(kf3, qf[3], s);

        // V^T A-frags (row=d, k = kv offset hi*8+e)
        const f16x8 vf00 = *(const f16x8*)(Vp + (size_t)(lo) * N_ + kv0 + hi * 8);
        const f16x8 vf01 = *(const f16x8*)(Vp + (size_t)(lo) * N_ + kv0 + 16 + hi * 8);
        const f16x8 vf10 = *(const f16x8*)(Vp + (size_t)(32 + lo) * N_ + kv0 + hi * 8);
        const f16x8 vf11 = *(const f16x8*)(Vp + (size_t)(32 + lo) * N_ + kv0 + 16 + hi * 8);

        // ---- online softmax (lane owns 16 of the 32 kv for q=lo; other 16 in lane^32)
        float tmax = s[0];
        #pragma unroll
        for (int r = 1; r < 16; ++r) tmax = fmaxf(tmax, s[r]);
        tmax = fmaxf(tmax, __shfl_xor(tmax, 32, 64));
        const float mn = fmaxf(m, tmax);
        const float corr = __expf(m - mn);
        m = mn;
        float p[16];
        float rs = 0.f;
        #pragma unroll
        for (int r = 0; r < 16; ++r) { p[r] = __expf(s[r] - mn); rs += p[r]; }
        rs += __shfl_xor(rs, 32, 64);
        lsum = lsum * corr + rs;
        #pragma unroll
        for (int r = 0; r < 16; ++r) { o0[r] *= corr; o1[r] *= corr; }

        // ---- P -> LDS: row q=lo; reg pairs (2i,2i+1) are consecutive kv:
        // kv_pair_base = ((i&1)<<1) + ((i>>1)<<3) + 4*hi  ->  {0,2,8,10,16,18,24,26}+4hi
        #pragma unroll
        for (int i = 0; i < 8; ++i) {
            const int kvp = ((i & 1) << 1) + ((i >> 1) << 3) + (hi << 2);
            const f16 h0 = (f16)p[2 * i];
            const f16 h1 = (f16)p[2 * i + 1];
            const unsigned w = (unsigned)__builtin_bit_cast(unsigned short, h0) |
                               ((unsigned)__builtin_bit_cast(unsigned short, h1) << 16);
            *(unsigned*)(pw + lo * 36 + kvp) = w;
        }
        // ---- PV B-frags: col=q=lo, k = kv = hi*8+e (contiguous 16B reads)
        const f16x8 pb1 = *(const f16x8*)(pw + lo * 36 + hi * 8);
        const f16x8 pb2 = *(const f16x8*)(pw + lo * 36 + 16 + hi * 8);

        // ---- O^T += V^T . P^T
        o0 = MFMA32(vf00, pb1, o0);
        o0 = MFMA32(vf01, pb2, o0);
        o1 = MFMA32(vf10, pb1, o1);
        o1 = MFMA32(vf11, pb2, o1);
    }

    // ---- epilogue: normalize, write f16 out (lane's q = lo is one row n)
    const int b = bh >> 4;
    const int h = bh & (H_ - 1);
    const float inv = 1.f / lsum;
    f16* outp = AO + ((size_t)(b * N_ + q0 + lo)) * C_ + h * D_;
    #pragma unroll
    for (int dh = 0; dh < 2; ++dh) {
        #pragma unroll
        for (int j = 0; j < 4; ++j) {
            const int d0 = dh * 32 + 8 * j + 4 * hi;
            f16x4 st;
            #pragma unroll
            for (int e = 0; e < 4; ++e) {
                const float v = (dh == 0 ? o0[4 * j + e] : o1[4 * j + e]) * inv;
                st[e] = (f16)v;
            }
            *(f16x4*)(outp + d0) = st;
        }
    }
}

extern "C" void kernel_launch(void* const* d_in, const int* in_sizes, int n_in,
                              void* d_out, int out_size, void* d_ws, size_t ws_size,
                              hipStream_t stream) {
    const float* x         = (const float*)d_in[0];
    const float* qkv_w     = (const float*)d_in[1];
    const float* qkv_b     = (const float*)d_in[2];
    const float* bias_mask = (const float*)d_in[3];
    const float* proj_w    = (const float*)d_in[4];
    const float* proj_b    = (const float*)d_in[5];
    float* out = (float*)d_out;

    const size_t NE = (size_t)B_ * H_ * N_ * D_;   // 8388608
    f16* Xh = (f16*)d_ws;
    f16* Wh = Xh + NE;              // 3145728
    f16* Ph = Wh + NW1_;            // 1048576
    f16* Qh = Ph + NW2_;
    f16* Kh = Qh + NE;
    f16* Vt = Kh + NE;
    f16* AOh = Vt + NE;             // total ~72 MiB (r3-validated layout)

    dim3 blk(256);
    convert_kernel<<<12288, blk, 0, stream>>>(x, qkv_w, proj_w, Xh, Wh, Ph);
    qkv_gemm_f16<<<dim3(64, 24), blk, 0, stream>>>(Xh, Wh, qkv_b, bias_mask, Qh, Kh, Vt);
    attn_fa3_kernel<<<dim3(N_ / 128, B_ * H_), blk, 0, stream>>>(Qh, Kh, Vt, AOh);
    proj_gemm_f16<<<dim3(64, 8), blk, 0, stream>>>(AOh, Ph, proj_b, out);
}